// Round 2
// baseline (85621.692 us; speedup 1.0000x reference)
//
#include <hip/hip_runtime.h>

#define C_  512
#define T_  8192
#define M_  5
#define H_  16
#define CM_ (C_ * M_)   // 2560

__device__ unsigned g_flag;   // heater epoch flag (only changes matter)

// lgkmcnt(0)-only barrier: LDS ops visible, global loads stay in flight.
__device__ __forceinline__ void bar_lgkm() {
    __asm__ volatile("s_waitcnt lgkmcnt(0)\n\ts_barrier" ::: "memory");
}

// x + dpp_move(x, ctrl): cross-lane add at VALU latency (no DS pipe).
#define DPP_ADD(x, ctrl)                                                      \
    ((x) + __int_as_float(__builtin_amdgcn_update_dpp(                        \
         0, __float_as_int(x), (ctrl), 0xf, 0xf, true)))
// raw dpp move (partner's value), VALU latency
#define DPP_MOV(x, ctrl)                                                      \
    __int_as_float(__builtin_amdgcn_update_dpp(                               \
         0, __float_as_int(x), (ctrl), 0xf, 0xf, true))
// ds_swizzle XOR exchange (bitmode): imm = (xor<<10) | 0x1F
#define SWZ(x, imm)                                                           \
    __int_as_float(__builtin_amdgcn_ds_swizzle(__float_as_int(x), (imm)))
// ctrl: row_shr:N = 0x110+N (data moves to HIGHER lanes; row sum lands at
// lane 15 of each 16-lane row), quad_perm XOR1 = 0xB1, XOR2 = 0x4E.

// ---------------------------------------------------------------------------
// Pre-kernel: hx[t][j] = b1[j] + sum_c x[c,t] * W1[c,j]
// ---------------------------------------------------------------------------
__global__ __launch_bounds__(256) void hx_kernel(
    const float* __restrict__ x, const float* __restrict__ W1,
    const float* __restrict__ b1, float* __restrict__ hx)
{
    __shared__ float xs[64][65];
    __shared__ __align__(16) float w1s[64][16];
    const int tid = threadIdx.x;
    const int t0  = blockIdx.x * 64;
    const int tl  = tid & 63;
    const int jg  = tid >> 6;

    float acc[4];
#pragma unroll
    for (int jj = 0; jj < 4; ++jj) acc[jj] = b1[jg * 4 + jj];

    for (int c0 = 0; c0 < C_; c0 += 64) {
#pragma unroll
        for (int ii = 0; ii < 16; ++ii) {
            int r = jg * 16 + ii;
            xs[r][tl] = x[(size_t)(c0 + r) * T_ + t0 + tl];
        }
#pragma unroll
        for (int ii = 0; ii < 4; ++ii) {
            int idx = tid * 4 + ii;
            ((float*)w1s)[idx] = W1[(size_t)c0 * H_ + idx];
        }
        __syncthreads();
#pragma unroll
        for (int i = 0; i < 64; ++i) {
            float s = xs[i][tl];
            float4 w = *(const float4*)&w1s[i][jg * 4];
            acc[0] = fmaf(s, w.x, acc[0]);
            acc[1] = fmaf(s, w.y, acc[1]);
            acc[2] = fmaf(s, w.z, acc[2]);
            acc[3] = fmaf(s, w.w, acc[3]);
        }
        __syncthreads();
    }
    float4 o; o.x = acc[0]; o.y = acc[1]; o.z = acc[2]; o.w = acc[3];
    *(float4*)&hx[(size_t)(t0 + tl) * H_ + jg * 4] = o;
}

// load 10 consecutive floats (8B-aligned) as 5x float2
#define LOAD10(dst, ptr)                                                      \
  { const float2* _p2 = (const float2*)(ptr);                                 \
    float2 _a0 = _p2[0], _a1 = _p2[1], _a2 = _p2[2], _a3 = _p2[3],            \
           _a4 = _p2[4];                                                      \
    dst[0] = _a0.x; dst[1] = _a0.y; dst[2] = _a1.x; dst[3] = _a1.y;           \
    dst[4] = _a2.x; dst[5] = _a2.y; dst[6] = _a3.x; dst[7] = _a3.y;           \
    dst[8] = _a4.x; dst[9] = _a4.y; }

// ---------------------------------------------------------------------------
// Scan, ONE barrier / step:
//   pre-bar : q from rh-regs -> ema/d/s -> g[j]=d·W1 partials ->
//             wave reduce-scatter (2 DPP quad stages + 2 ds_swizzle XOR
//             stages) -> ds_add_f32 into Gb[PH][j] / ssb[PH]; zero buf PH+1.
//   post-bar: every thread broadcast-reads G[16]+ss, computes scale, stores
//             out, and redundantly builds rh[16] in registers (no 2nd bar).
// G buffers rotate with period 4 (matches the 4-step unroll): step t
// accumulates buf t&3, reads it post-bar, zeroes buf (t+1)&3 pre-bar.
// ---------------------------------------------------------------------------
#define STEP(TT, PH)                                                          \
  {                                                                           \
    const int tt = (TT);                                                      \
    /* hx prefetch: row tt+2 -> slot PH&1 (consumed end of step tt+1) */      \
    {                                                                         \
      int tn = tt + 2; if (tn > T_ - 1) tn = T_ - 1;                          \
      const float4* hp = (const float4*)(hx + (size_t)tn * H_);               \
      hxq[PH & 1][0] = hp[0]; hxq[PH & 1][1] = hp[1];                         \
      hxq[PH & 1][2] = hp[2]; hxq[PH & 1][3] = hp[3];                         \
    }                                                                         \
    /* ---- q = W2^T rh + b2 (rh in registers) ---- */                        \
    float qa0 = b2c0, qb0 = 0.f, qa1 = b2c1, qb1 = 0.f;                       \
    _Pragma("unroll")                                                         \
    for (int j = 0; j < 8; ++j) {                                             \
        qa0 = fmaf(rh[2*j],   w2c0[2*j],   qa0);                              \
        qb0 = fmaf(rh[2*j+1], w2c0[2*j+1], qb0);                              \
        qa1 = fmaf(rh[2*j],   w2c1[2*j],   qa1);                              \
        qb1 = fmaf(rh[2*j+1], w2c1[2*j+1], qb1);                              \
    }                                                                         \
    const float q0 = qa0 + qb0, q1 = qa1 + qb1;                               \
    powv *= 0.95f;                                                            \
    const float mq0 = 0.05f * q0, mq1 = 0.05f * q1;                           \
    _Pragma("unroll")                                                         \
    for (int m = 0; m < M_; ++m) {                                            \
        ema0[m] = fmaf(ema0[m], 0.95f, mq0 * kq[PH][m]);                      \
        ema1[m] = fmaf(ema1[m], 0.95f, mq1 * kq[PH][5 + m]);                  \
    }                                                                         \
    float d0 = 0.f, d1 = 0.f, s0 = 0.f, s1 = 0.f;                             \
    _Pragma("unroll")                                                         \
    for (int m = 0; m < M_; ++m) {                                            \
        d0 = fmaf(ema0[m], vq[PH][m],     d0);                                \
        d1 = fmaf(ema1[m], vq[PH][5 + m], d1);                                \
        s0 = fmaf(ema0[m], ema0[m], s0);                                      \
        s1 = fmaf(ema1[m], ema1[m], s1);                                      \
    }                                                                         \
    /* K/V prefetch for row tt+4 — AFTER kq[PH]/vq[PH] were consumed */       \
    if (tt + 4 < T_) {                                                        \
        LOAD10(kq[PH], kp); LOAD10(vq[PH], vp);                               \
        kp += CM_; vp += CM_;                                                 \
    }                                                                         \
    /* ---- g partials + wave reduce-scatter over j=0..15 ---- */             \
    float g16[16];                                                            \
    _Pragma("unroll")                                                         \
    for (int j = 0; j < 16; ++j)                                              \
        g16[j] = fmaf(d0, w1c0[j], d1 * w1c1[j]);                             \
    float h8[8];                                                              \
    _Pragma("unroll")                                                         \
    for (int k = 0; k < 8; ++k) {                                             \
        float gv = pr0 ? g16[2*k]   : g16[2*k+1];                             \
        float kv = pr0 ? g16[2*k+1] : g16[2*k];                               \
        h8[k] = kv + DPP_MOV(gv, 0xB1);      /* quad_perm XOR1 */             \
    }                                                                         \
    float h4[4];                                                              \
    _Pragma("unroll")                                                         \
    for (int k = 0; k < 4; ++k) {                                             \
        float gv = pr1 ? h8[2*k]   : h8[2*k+1];                               \
        float kv = pr1 ? h8[2*k+1] : h8[2*k];                                 \
        h4[k] = kv + DPP_MOV(gv, 0x4E);      /* quad_perm XOR2 */             \
    }                                                                         \
    float h2[2];                                                              \
    _Pragma("unroll")                                                         \
    for (int k = 0; k < 2; ++k) {                                             \
        float gv = pr2 ? h4[2*k]   : h4[2*k+1];                               \
        float kv = pr2 ? h4[2*k+1] : h4[2*k];                                 \
        h2[k] = kv + SWZ(gv, 0x101F);        /* ds_swizzle XOR4 */            \
    }                                                                         \
    {                                                                         \
        float gv = pr3 ? h2[0] : h2[1];                                       \
        float kv = pr3 ? h2[1] : h2[0];                                       \
        float hv = kv + SWZ(gv, 0x201F);     /* ds_swizzle XOR8 */            \
        /* hv = row(16-lane) sum for j = tid&15; 16 adds/addr total */        \
        atomicAdd(&Gb[PH][j15], hv);                                          \
    }                                                                         \
    float ssv = s0 + s1;                                                      \
    ssv = DPP_ADD(ssv, 0x111);  /* row_shr:1 */                               \
    ssv = DPP_ADD(ssv, 0x112);  /* row_shr:2 */                               \
    ssv = DPP_ADD(ssv, 0x114);  /* row_shr:4 */                               \
    ssv = DPP_ADD(ssv, 0x118);  /* row_shr:8 -> lane15 of row = row sum */    \
    if (j15 == 15) atomicAdd(&ssb[PH], ssv);                                  \
    if (tid < 16) Gb[(PH + 1) & 3][tid] = 0.f;                                \
    else if (tid == 16) ssb[(PH + 1) & 3] = 0.f;                              \
    bar_lgkm();                                                               \
    /* ---- post-barrier: broadcast reads, scale, out, rh in regs ---- */     \
    const float4* gp = (const float4*)Gb[PH];                                 \
    float4 G0 = gp[0], G1 = gp[1], G2 = gp[2], G3 = gp[3];                    \
    float ssT   = ssb[PH];                                                    \
    float bias  = 1.0f - powv;                                                \
    float nr    = __builtin_amdgcn_sqrtf(ssT);                                \
    float scl   = __builtin_amdgcn_rcpf(fmaf(1e-12f, bias, nr));              \
    o0[tt] = scl * d0;                                                        \
    o1[tt] = scl * d1;                                                        \
    {                                                                         \
      float4 ha = hxq[(PH + 1) & 1][0], hb = hxq[(PH + 1) & 1][1],            \
             hc = hxq[(PH + 1) & 1][2], hd = hxq[(PH + 1) & 1][3];            \
      rh[0]  = fmaxf(fmaf(scl, G0.x, ha.x), 0.f);                             \
      rh[1]  = fmaxf(fmaf(scl, G0.y, ha.y), 0.f);                             \
      rh[2]  = fmaxf(fmaf(scl, G0.z, ha.z), 0.f);                             \
      rh[3]  = fmaxf(fmaf(scl, G0.w, ha.w), 0.f);                             \
      rh[4]  = fmaxf(fmaf(scl, G1.x, hb.x), 0.f);                             \
      rh[5]  = fmaxf(fmaf(scl, G1.y, hb.y), 0.f);                             \
      rh[6]  = fmaxf(fmaf(scl, G1.z, hb.z), 0.f);                             \
      rh[7]  = fmaxf(fmaf(scl, G1.w, hb.w), 0.f);                             \
      rh[8]  = fmaxf(fmaf(scl, G2.x, hc.x), 0.f);                             \
      rh[9]  = fmaxf(fmaf(scl, G2.y, hc.y), 0.f);                             \
      rh[10] = fmaxf(fmaf(scl, G2.z, hc.z), 0.f);                             \
      rh[11] = fmaxf(fmaf(scl, G2.w, hc.w), 0.f);                             \
      rh[12] = fmaxf(fmaf(scl, G3.x, hd.x), 0.f);                             \
      rh[13] = fmaxf(fmaf(scl, G3.y, hd.y), 0.f);                             \
      rh[14] = fmaxf(fmaf(scl, G3.z, hd.z), 0.f);                             \
      rh[15] = fmaxf(fmaf(scl, G3.w, hd.w), 0.f);                             \
    }                                                                         \
  }

__global__ __launch_bounds__(256, 1) void scan_kernel(
    const float* __restrict__ hx, const float* __restrict__ Kp,
    const float* __restrict__ Vp, const float* __restrict__ W1,
    const float* __restrict__ W2, const float* __restrict__ b2,
    float* __restrict__ out)
{
    const int tid = threadIdx.x;

    if (blockIdx.x != 0) {
        // ---- heater: keep all CUs busy so DPM boosts SCLK. tid0 is the
        // only global poller (~1 poll / 1024 cyc / block); everyone else
        // spins on the LDS flag. No shared hot cacheline (R6 post-mortem).
        __shared__ unsigned hflag;
        if (tid == 0) hflag = 0;
        __syncthreads();
        __builtin_amdgcn_s_setprio(0);
        unsigned start = 0;
        if (tid == 0)
            start = __hip_atomic_load(&g_flag, __ATOMIC_RELAXED,
                                      __HIP_MEMORY_SCOPE_AGENT);
        float a0 = (float)(tid + blockIdx.x) * 1e-6f + 1.0f;
        float a1 = a0 + 0.25f, a2 = a0 + 0.5f, a3 = a0 + 0.75f;
        const float b = 1.0000001f, cc = 1e-7f;
        for (int it = 0; it < 100000; ++it) {
#pragma unroll
            for (int k = 0; k < 128; ++k) {
                a0 = fmaf(a0, b, cc); a1 = fmaf(a1, b, cc);
                a2 = fmaf(a2, b, cc); a3 = fmaf(a3, b, cc);
            }
            if (tid == 0 &&
                __hip_atomic_load(&g_flag, __ATOMIC_RELAXED,
                                  __HIP_MEMORY_SCOPE_AGENT) != start)
                __hip_atomic_store(&hflag, 1u, __ATOMIC_RELAXED,
                                   __HIP_MEMORY_SCOPE_WORKGROUP);
            if (__hip_atomic_load(&hflag, __ATOMIC_RELAXED,
                                  __HIP_MEMORY_SCOPE_WORKGROUP)) break;
        }
        if (__float_as_uint(a0 + a1 + a2 + a3) == 0xDEADBEEFu)  // keep live
            __hip_atomic_fetch_add(&g_flag, 0u, __ATOMIC_RELAXED,
                                   __HIP_MEMORY_SCOPE_AGENT);
        return;
    }

    __builtin_amdgcn_s_setprio(3);   // scan waves win issue arbitration

    const int c0  = 2 * tid, c1 = 2 * tid + 1;
    const int j15 = tid & 15;
    const bool pr0 = (tid & 1), pr1 = (tid & 2), pr2 = (tid & 4),
               pr3 = (tid & 8);

    __shared__ __align__(16) float Gb[4][16];   // rotating u-partial buffers
    __shared__ float ssb[4];                    // rotating ss buffers

    // per-thread weight slices
    float w2c0[16], w2c1[16], w1c0[16], w1c1[16];
#pragma unroll
    for (int j = 0; j < 16; ++j) {
        w2c0[j] = W2[(size_t)j * C_ + c0];
        w2c1[j] = W2[(size_t)j * C_ + c1];
    }
    {
        const float4* p0 = (const float4*)&W1[(size_t)c0 * H_];
        const float4* p1 = (const float4*)&W1[(size_t)c1 * H_];
#pragma unroll
        for (int k = 0; k < 4; ++k) {
            float4 a = p0[k], b = p1[k];
            w1c0[4*k] = a.x; w1c0[4*k+1] = a.y; w1c0[4*k+2] = a.z;
            w1c0[4*k+3] = a.w;
            w1c1[4*k] = b.x; w1c1[4*k+1] = b.y; w1c1[4*k+2] = b.z;
            w1c1[4*k+3] = b.w;
        }
    }
    const float b2c0 = b2[c0], b2c1 = b2[c1];

    float ema0[M_] = {0, 0, 0, 0, 0};
    float ema1[M_] = {0, 0, 0, 0, 0};
    float powv = 1.0f;

    // K/V register prefetch, 4 steps deep
    const float* kp = Kp + 10 * tid;
    const float* vp = Vp + 10 * tid;
    float kq[4][10], vq[4][10];
#pragma unroll
    for (int ph = 0; ph < 4; ++ph) {
        LOAD10(kq[ph], kp + ph * CM_);
        LOAD10(vq[ph], vp + ph * CM_);
    }
    kp += 4 * CM_; vp += 4 * CM_;

    // rh seed: y_prev = 0 -> rh = relu(hx[0]); every thread holds all 16
    float rh[16];
    {
        const float4* p = (const float4*)hx;
        float4 a = p[0], b = p[1], c = p[2], d = p[3];
        rh[0]  = fmaxf(a.x, 0.f); rh[1]  = fmaxf(a.y, 0.f);
        rh[2]  = fmaxf(a.z, 0.f); rh[3]  = fmaxf(a.w, 0.f);
        rh[4]  = fmaxf(b.x, 0.f); rh[5]  = fmaxf(b.y, 0.f);
        rh[6]  = fmaxf(b.z, 0.f); rh[7]  = fmaxf(b.w, 0.f);
        rh[8]  = fmaxf(c.x, 0.f); rh[9]  = fmaxf(c.y, 0.f);
        rh[10] = fmaxf(c.z, 0.f); rh[11] = fmaxf(c.w, 0.f);
        rh[12] = fmaxf(d.x, 0.f); rh[13] = fmaxf(d.y, 0.f);
        rh[14] = fmaxf(d.z, 0.f); rh[15] = fmaxf(d.w, 0.f);
    }

    // hx ping-pong preload: slot 1 <- row 1 (consumed at end of step 0)
    float4 hxq[2][4];
    {
        const float4* p = (const float4*)(hx + H_);
        hxq[1][0] = p[0]; hxq[1][1] = p[1];
        hxq[1][2] = p[2]; hxq[1][3] = p[3];
    }

    if (tid < 16) {
        Gb[0][tid] = 0.f; Gb[1][tid] = 0.f;
        Gb[2][tid] = 0.f; Gb[3][tid] = 0.f;
    } else if (tid == 16) {
        ssb[0] = 0.f; ssb[1] = 0.f; ssb[2] = 0.f; ssb[3] = 0.f;
    }
    __syncthreads();

    float* o0 = out + (size_t)c0 * T_;
    float* o1 = out + (size_t)c1 * T_;

    for (int t = 0; t < T_; t += 4) {
        STEP(t,     0)
        STEP(t + 1, 1)
        STEP(t + 2, 2)
        STEP(t + 3, 3)
    }

    if (tid == 0)
        __hip_atomic_fetch_add(&g_flag, 1u, __ATOMIC_RELAXED,
                               __HIP_MEMORY_SCOPE_AGENT);
}

extern "C" void kernel_launch(void* const* d_in, const int* in_sizes, int n_in,
                              void* d_out, int out_size, void* d_ws, size_t ws_size,
                              hipStream_t stream)
{
    (void)in_sizes; (void)n_in; (void)out_size; (void)ws_size;
    const float* y  = (const float*)d_in[0];
    const float* K  = (const float*)d_in[1];
    const float* V  = (const float*)d_in[2];
    const float* W1 = (const float*)d_in[3];
    const float* b1 = (const float*)d_in[4];
    const float* W2 = (const float*)d_in[5];
    const float* b2 = (const float*)d_in[6];
    float* out = (float*)d_out;
    float* hx  = (float*)d_ws;                 // T*16 floats = 512 KB

    hipLaunchKernelGGL(hx_kernel, dim3(T_ / 64), dim3(256), 0, stream,
                       y, W1, b1, hx);
    // 1 scan block + 256 heaters ≈ 1 heater per CU; all co-resident.
    hipLaunchKernelGGL(scan_kernel, dim3(257), dim3(256), 0, stream,
                       hx, K, V, W1, W2, b2, out);
}

// Round 5
// 85249.249 us; speedup vs baseline: 1.0044x; 1.0044x over previous
//
#include <hip/hip_runtime.h>

#define C_  512
#define T_  8192
#define M_  5
#define H_  16
#define CM_ (C_ * M_)   // 2560

__device__ unsigned g_flag;   // heater epoch flag (only changes matter)

// lgkmcnt(0)-only barrier: LDS ops visible, global loads stay in flight.
__device__ __forceinline__ void bar_lgkm() {
    __asm__ volatile("s_waitcnt lgkmcnt(0)\n\ts_barrier" ::: "memory");
}

// x + dpp_move(x, ctrl): cross-lane add at VALU latency (no DS pipe).
#define DPP_ADD(x, ctrl)                                                      \
    ((x) + __int_as_float(__builtin_amdgcn_update_dpp(                        \
         0, __float_as_int(x), (ctrl), 0xf, 0xf, true)))
// raw dpp move (partner's value), VALU latency
#define DPP_MOV(x, ctrl)                                                      \
    __int_as_float(__builtin_amdgcn_update_dpp(                               \
         0, __float_as_int(x), (ctrl), 0xf, 0xf, true))
// ds_swizzle XOR exchange (bitmode): imm = (xor<<10) | 0x1F, within 32 lanes
#define SWZ(x, imm)                                                           \
    __int_as_float(__builtin_amdgcn_ds_swizzle(__float_as_int(x), (imm)))
// ctrl: row_shr:N = 0x110+N (toward higher lanes), row_bcast15 = 0x142,
// row_bcast31 = 0x143, quad_perm XOR1 = 0xB1, XOR2 = 0x4E.

// ---------------------------------------------------------------------------
// Pre-kernel: hx[t][j] = b1[j] + sum_c x[c,t] * W1[c,j]
// ---------------------------------------------------------------------------
__global__ __launch_bounds__(256) void hx_kernel(
    const float* __restrict__ x, const float* __restrict__ W1,
    const float* __restrict__ b1, float* __restrict__ hx)
{
    __shared__ float xs[64][65];
    __shared__ __align__(16) float w1s[64][16];
    const int tid = threadIdx.x;
    const int t0  = blockIdx.x * 64;
    const int tl  = tid & 63;
    const int jg  = tid >> 6;

    float acc[4];
#pragma unroll
    for (int jj = 0; jj < 4; ++jj) acc[jj] = b1[jg * 4 + jj];

    for (int c0 = 0; c0 < C_; c0 += 64) {
#pragma unroll
        for (int ii = 0; ii < 16; ++ii) {
            int r = jg * 16 + ii;
            xs[r][tl] = x[(size_t)(c0 + r) * T_ + t0 + tl];
        }
#pragma unroll
        for (int ii = 0; ii < 4; ++ii) {
            int idx = tid * 4 + ii;
            ((float*)w1s)[idx] = W1[(size_t)c0 * H_ + idx];
        }
        __syncthreads();
#pragma unroll
        for (int i = 0; i < 64; ++i) {
            float s = xs[i][tl];
            float4 w = *(const float4*)&w1s[i][jg * 4];
            acc[0] = fmaf(s, w.x, acc[0]);
            acc[1] = fmaf(s, w.y, acc[1]);
            acc[2] = fmaf(s, w.z, acc[2]);
            acc[3] = fmaf(s, w.w, acc[3]);
        }
        __syncthreads();
    }
    float4 o; o.x = acc[0]; o.y = acc[1]; o.z = acc[2]; o.w = acc[3];
    *(float4*)&hx[(size_t)(t0 + tl) * H_ + jg * 4] = o;
}

// load 10 consecutive floats (8B-aligned) as 5x float2
#define LOAD10(dst, ptr)                                                      \
  { const float2* _p2 = (const float2*)(ptr);                                 \
    float2 _a0 = _p2[0], _a1 = _p2[1], _a2 = _p2[2], _a3 = _p2[3],            \
           _a4 = _p2[4];                                                      \
    dst[0] = _a0.x; dst[1] = _a0.y; dst[2] = _a1.x; dst[3] = _a1.y;           \
    dst[4] = _a2.x; dst[5] = _a2.y; dst[6] = _a3.x; dst[7] = _a3.y;           \
    dst[8] = _a4.x; dst[9] = _a4.y; }

// ---------------------------------------------------------------------------
// Scan, ONE barrier / step, NO LDS atomics:
//   pre-bar : q from rh-regs -> ema/d/s -> g[j] partials -> FULL wave fold
//             (DPP XOR1/2, swizzle XOR4/8/16, shfl XOR32) -> lanes 0..15 of
//             each wave plain-write wave-total G to Gw[p][w*16+j]; ss via
//             R0-verified DPP chain -> lane63 writes Gw[p][64+w].
//   post-bar: every thread broadcast-reads 4x16 G + 4 ss, folds across
//             waves, computes scale, stores out, builds rh[16] in regs.
// Double-buffer parity p = step&1: readers of buf p are separated from the
// next writers of buf p by two barriers. Plain writes -> no zeroing.
// ---------------------------------------------------------------------------
#define STEP(TT, PH)                                                          \
  {                                                                           \
    const int tt = (TT);                                                      \
    const int bp = (PH) & 1;                                                  \
    /* hx prefetch: row tt+2 -> slot PH&1 (consumed end of step tt+1) */      \
    {                                                                         \
      int tn = tt + 2; if (tn > T_ - 1) tn = T_ - 1;                          \
      const float4* hp = (const float4*)(hx + (size_t)tn * H_);               \
      _Pragma("unroll")                                                       \
      for (int k = 0; k < 4; ++k) {                                           \
          float4 hq = hp[k];                                                  \
          hxv[bp][4*k+0] = hq.x; hxv[bp][4*k+1] = hq.y;                       \
          hxv[bp][4*k+2] = hq.z; hxv[bp][4*k+3] = hq.w;                       \
      }                                                                       \
    }                                                                         \
    /* ---- q = W2^T rh + b2 (rh in registers) ---- */                        \
    float qa0 = b2c0, qb0 = 0.f, qa1 = b2c1, qb1 = 0.f;                       \
    _Pragma("unroll")                                                         \
    for (int j = 0; j < 8; ++j) {                                             \
        qa0 = fmaf(rh[2*j],   w2c0[2*j],   qa0);                              \
        qb0 = fmaf(rh[2*j+1], w2c0[2*j+1], qb0);                              \
        qa1 = fmaf(rh[2*j],   w2c1[2*j],   qa1);                              \
        qb1 = fmaf(rh[2*j+1], w2c1[2*j+1], qb1);                              \
    }                                                                         \
    const float q0 = qa0 + qb0, q1 = qa1 + qb1;                               \
    powv *= 0.95f;                                                            \
    const float mq0 = 0.05f * q0, mq1 = 0.05f * q1;                           \
    _Pragma("unroll")                                                         \
    for (int m = 0; m < M_; ++m) {                                            \
        ema0[m] = fmaf(ema0[m], 0.95f, mq0 * kq[PH][m]);                      \
        ema1[m] = fmaf(ema1[m], 0.95f, mq1 * kq[PH][5 + m]);                  \
    }                                                                         \
    float d0 = 0.f, d1 = 0.f, s0 = 0.f, s1 = 0.f;                             \
    _Pragma("unroll")                                                         \
    for (int m = 0; m < M_; ++m) {                                            \
        d0 = fmaf(ema0[m], vq[PH][m],     d0);                                \
        d1 = fmaf(ema1[m], vq[PH][5 + m], d1);                                \
        s0 = fmaf(ema0[m], ema0[m], s0);                                      \
        s1 = fmaf(ema1[m], ema1[m], s1);                                      \
    }                                                                         \
    /* K/V prefetch for row tt+4 — AFTER kq[PH]/vq[PH] were consumed */       \
    if (tt + 4 < T_) {                                                        \
        LOAD10(kq[PH], kp); LOAD10(vq[PH], vp);                               \
        kp += CM_; vp += CM_;                                                 \
    }                                                                         \
    /* ---- g partials + FULL wave fold over j=0..15 ---- */                  \
    float g16[16];                                                            \
    _Pragma("unroll")                                                         \
    for (int j = 0; j < 16; ++j)                                              \
        g16[j] = fmaf(d0, w1c0[j], d1 * w1c1[j]);                             \
    float h8[8];                                                              \
    _Pragma("unroll")                                                         \
    for (int k = 0; k < 8; ++k) {                                             \
        float gv = pr0 ? g16[2*k]   : g16[2*k+1];                             \
        float kv = pr0 ? g16[2*k+1] : g16[2*k];                               \
        h8[k] = kv + DPP_MOV(gv, 0xB1);      /* quad_perm XOR1 */             \
    }                                                                         \
    float h4[4];                                                              \
    _Pragma("unroll")                                                         \
    for (int k = 0; k < 4; ++k) {                                             \
        float gv = pr1 ? h8[2*k]   : h8[2*k+1];                               \
        float kv = pr1 ? h8[2*k+1] : h8[2*k];                                 \
        h4[k] = kv + DPP_MOV(gv, 0x4E);      /* quad_perm XOR2 */             \
    }                                                                         \
    float h2[2];                                                              \
    _Pragma("unroll")                                                         \
    for (int k = 0; k < 2; ++k) {                                             \
        float gv = pr2 ? h4[2*k]   : h4[2*k+1];                               \
        float kv = pr2 ? h4[2*k+1] : h4[2*k];                                 \
        h2[k] = kv + SWZ(gv, 0x101F);        /* ds_swizzle XOR4 */            \
    }                                                                         \
    float hv;                                                                 \
    {                                                                         \
        float gv = pr3 ? h2[0] : h2[1];                                       \
        float kv = pr3 ? h2[1] : h2[0];                                       \
        hv = kv + SWZ(gv, 0x201F);           /* XOR8: row sum, j=tid&15 */    \
    }                                                                         \
    hv += SWZ(hv, 0x401F);                   /* XOR16: rows within half */    \
    hv += __shfl_xor(hv, 32, 64);            /* XOR32: full wave total */     \
    if (l63 < 16) Gw[bp][wv16 + l63] = hv;                                    \
    float ssv = s0 + s1;                                                      \
    ssv = DPP_ADD(ssv, 0x111);  /* row_shr:1 */                               \
    ssv = DPP_ADD(ssv, 0x112);  /* row_shr:2 */                               \
    ssv = DPP_ADD(ssv, 0x114);  /* row_shr:4 */                               \
    ssv = DPP_ADD(ssv, 0x118);  /* row_shr:8 */                               \
    ssv = DPP_ADD(ssv, 0x142);  /* row_bcast15 */                             \
    ssv = DPP_ADD(ssv, 0x143);  /* row_bcast31 -> lane63 = wave total */      \
    if (l63 == 63) Gw[bp][64 + wv] = ssv;                                     \
    bar_lgkm();                                                               \
    /* ---- post-barrier: broadcast reads, fold waves, scale, out, rh ---- */ \
    float Gs[16];                                                             \
    {                                                                         \
      const float4* gq = (const float4*)&Gw[bp][0];                           \
      _Pragma("unroll")                                                       \
      for (int q4 = 0; q4 < 4; ++q4) {                                        \
          float4 u0 = gq[q4], u1 = gq[4+q4], u2 = gq[8+q4], u3 = gq[12+q4];   \
          Gs[4*q4+0] = (u0.x+u1.x)+(u2.x+u3.x);                               \
          Gs[4*q4+1] = (u0.y+u1.y)+(u2.y+u3.y);                               \
          Gs[4*q4+2] = (u0.z+u1.z)+(u2.z+u3.z);                               \
          Gs[4*q4+3] = (u0.w+u1.w)+(u2.w+u3.w);                               \
      }                                                                       \
    }                                                                         \
    float4 SQ = *(const float4*)&Gw[bp][64];                                  \
    float ssT   = (SQ.x + SQ.y) + (SQ.z + SQ.w);                              \
    float bias  = 1.0f - powv;                                                \
    float nr    = __builtin_amdgcn_sqrtf(ssT);                                \
    float scl   = __builtin_amdgcn_rcpf(fmaf(1e-12f, bias, nr));              \
    o0[tt] = scl * d0;                                                        \
    o1[tt] = scl * d1;                                                        \
    _Pragma("unroll")                                                         \
    for (int j = 0; j < 16; ++j)                                              \
        rh[j] = fmaxf(fmaf(scl, Gs[j], hxv[(PH + 1) & 1][j]), 0.f);           \
  }

__global__ __launch_bounds__(256, 1) void scan_kernel(
    const float* __restrict__ hx, const float* __restrict__ Kp,
    const float* __restrict__ Vp, const float* __restrict__ W1,
    const float* __restrict__ W2, const float* __restrict__ b2,
    float* __restrict__ out)
{
    const int tid = threadIdx.x;

    if (blockIdx.x != 0) {
        // ---- heater: keep all CUs busy so DPM boosts SCLK. tid0 is the
        // only global poller; everyone else spins on the LDS flag.
        // Cap kept at R2-proven 100k (R3/R4 post-mortem: the 400k raise is
        // the only delta between a completing container and two dead ones).
        __shared__ unsigned hflag;
        if (tid == 0) hflag = 0;
        __syncthreads();
        __builtin_amdgcn_s_setprio(0);
        unsigned start = 0;
        if (tid == 0)
            start = __hip_atomic_load(&g_flag, __ATOMIC_RELAXED,
                                      __HIP_MEMORY_SCOPE_AGENT);
        float a0 = (float)(tid + blockIdx.x) * 1e-6f + 1.0f;
        float a1 = a0 + 0.25f, a2 = a0 + 0.5f, a3 = a0 + 0.75f;
        const float b = 1.0000001f, cc = 1e-7f;
        for (int it = 0; it < 100000; ++it) {
#pragma unroll
            for (int k = 0; k < 128; ++k) {
                a0 = fmaf(a0, b, cc); a1 = fmaf(a1, b, cc);
                a2 = fmaf(a2, b, cc); a3 = fmaf(a3, b, cc);
            }
            if (tid == 0 &&
                __hip_atomic_load(&g_flag, __ATOMIC_RELAXED,
                                  __HIP_MEMORY_SCOPE_AGENT) != start)
                __hip_atomic_store(&hflag, 1u, __ATOMIC_RELAXED,
                                   __HIP_MEMORY_SCOPE_WORKGROUP);
            if (__hip_atomic_load(&hflag, __ATOMIC_RELAXED,
                                  __HIP_MEMORY_SCOPE_WORKGROUP)) break;
        }
        if (__float_as_uint(a0 + a1 + a2 + a3) == 0xDEADBEEFu)  // keep live
            __hip_atomic_fetch_add(&g_flag, 0u, __ATOMIC_RELAXED,
                                   __HIP_MEMORY_SCOPE_AGENT);
        return;
    }

    __builtin_amdgcn_s_setprio(3);   // scan waves win issue arbitration

    const int c0   = 2 * tid, c1 = 2 * tid + 1;
    const int l63  = tid & 63;
    const int wv   = tid >> 6;
    const int wv16 = wv * 16;
    const bool pr0 = (tid & 1), pr1 = (tid & 2), pr2 = (tid & 4),
               pr3 = (tid & 8);

    // [parity][w*16+j] = per-wave G totals; [parity][64+w] = per-wave ss
    __shared__ __align__(16) float Gw[2][68];

    // per-thread weight slices
    float w2c0[16], w2c1[16], w1c0[16], w1c1[16];
#pragma unroll
    for (int j = 0; j < 16; ++j) {
        w2c0[j] = W2[(size_t)j * C_ + c0];
        w2c1[j] = W2[(size_t)j * C_ + c1];
    }
    {
        const float4* p0 = (const float4*)&W1[(size_t)c0 * H_];
        const float4* p1 = (const float4*)&W1[(size_t)c1 * H_];
#pragma unroll
        for (int k = 0; k < 4; ++k) {
            float4 a = p0[k], b = p1[k];
            w1c0[4*k] = a.x; w1c0[4*k+1] = a.y; w1c0[4*k+2] = a.z;
            w1c0[4*k+3] = a.w;
            w1c1[4*k] = b.x; w1c1[4*k+1] = b.y; w1c1[4*k+2] = b.z;
            w1c1[4*k+3] = b.w;
        }
    }
    const float b2c0 = b2[c0], b2c1 = b2[c1];

    float ema0[M_] = {0, 0, 0, 0, 0};
    float ema1[M_] = {0, 0, 0, 0, 0};
    float powv = 1.0f;

    // K/V register prefetch, 4 steps deep
    const float* kp = Kp + 10 * tid;
    const float* vp = Vp + 10 * tid;
    float kq[4][10], vq[4][10];
#pragma unroll
    for (int ph = 0; ph < 4; ++ph) {
        LOAD10(kq[ph], kp + ph * CM_);
        LOAD10(vq[ph], vp + ph * CM_);
    }
    kp += 4 * CM_; vp += 4 * CM_;

    // rh seed: y_prev = 0 -> rh = relu(hx[0]); every thread holds all 16
    float rh[16];
    {
        const float4* p = (const float4*)hx;
#pragma unroll
        for (int k = 0; k < 4; ++k) {
            float4 a = p[k];
            rh[4*k+0] = fmaxf(a.x, 0.f); rh[4*k+1] = fmaxf(a.y, 0.f);
            rh[4*k+2] = fmaxf(a.z, 0.f); rh[4*k+3] = fmaxf(a.w, 0.f);
        }
    }

    // hx ping-pong preload: slot 1 <- row 1 (consumed at end of step 0)
    float hxv[2][16];
    {
        const float4* p = (const float4*)(hx + H_);
#pragma unroll
        for (int k = 0; k < 4; ++k) {
            float4 a = p[k];
            hxv[1][4*k+0] = a.x; hxv[1][4*k+1] = a.y;
            hxv[1][4*k+2] = a.z; hxv[1][4*k+3] = a.w;
        }
    }

    __syncthreads();

    float* o0 = out + (size_t)c0 * T_;
    float* o1 = out + (size_t)c1 * T_;

    for (int t = 0; t < T_; t += 4) {
        STEP(t,     0)
        STEP(t + 1, 1)
        STEP(t + 2, 2)
        STEP(t + 3, 3)
    }

    if (tid == 0)
        __hip_atomic_fetch_add(&g_flag, 1u, __ATOMIC_RELAXED,
                               __HIP_MEMORY_SCOPE_AGENT);
}

extern "C" void kernel_launch(void* const* d_in, const int* in_sizes, int n_in,
                              void* d_out, int out_size, void* d_ws, size_t ws_size,
                              hipStream_t stream)
{
    (void)in_sizes; (void)n_in; (void)out_size; (void)ws_size;
    const float* y  = (const float*)d_in[0];
    const float* K  = (const float*)d_in[1];
    const float* V  = (const float*)d_in[2];
    const float* W1 = (const float*)d_in[3];
    const float* b1 = (const float*)d_in[4];
    const float* W2 = (const float*)d_in[5];
    const float* b2 = (const float*)d_in[6];
    float* out = (float*)d_out;
    float* hx  = (float*)d_ws;                 // T*16 floats = 512 KB

    hipLaunchKernelGGL(hx_kernel, dim3(T_ / 64), dim3(256), 0, stream,
                       y, W1, b1, hx);
    // 1 scan block + 256 heaters ≈ 1 heater per CU; all co-resident.
    hipLaunchKernelGGL(scan_kernel, dim3(257), dim3(256), 0, stream,
                       hx, K, V, W1, W2, b2, out);
}

// Round 6
// 9619.134 us; speedup vs baseline: 8.9012x; 8.8625x over previous
//
#include <hip/hip_runtime.h>

#define C_  512
#define T_  8192
#define M_  5
#define H_  16
#define CM_ (C_ * M_)   // 2560

__device__ unsigned g_flag;   // heater epoch flag (only changes matter)

// lgkmcnt(0)-only barrier: LDS writes visible, global loads stay in flight.
__device__ __forceinline__ void bar_lgkm() {
    __asm__ volatile("s_waitcnt lgkmcnt(0)\n\ts_barrier" ::: "memory");
}

// x + dpp_move(x, ctrl): cross-lane add at VALU latency (no DS pipe).
#define DPP_ADD(x, ctrl)                                                      \
    ((x) + __int_as_float(__builtin_amdgcn_update_dpp(                        \
         0, __float_as_int(x), (ctrl), 0xf, 0xf, true)))
// ctrl: row_shr:N = 0x110+N, row_bcast15 = 0x142, row_bcast31 = 0x143.

// ---------------------------------------------------------------------------
// Pre-kernel: hx[t][j] = b1[j] + sum_c x[c,t] * W1[c,j]
// ---------------------------------------------------------------------------
__global__ __launch_bounds__(256) void hx_kernel(
    const float* __restrict__ x, const float* __restrict__ W1,
    const float* __restrict__ b1, float* __restrict__ hx)
{
    __shared__ float xs[64][65];
    __shared__ __align__(16) float w1s[64][16];
    const int tid = threadIdx.x;
    const int t0  = blockIdx.x * 64;
    const int tl  = tid & 63;
    const int jg  = tid >> 6;

    float acc[4];
#pragma unroll
    for (int jj = 0; jj < 4; ++jj) acc[jj] = b1[jg * 4 + jj];

    for (int c0 = 0; c0 < C_; c0 += 64) {
#pragma unroll
        for (int ii = 0; ii < 16; ++ii) {
            int r = jg * 16 + ii;
            xs[r][tl] = x[(size_t)(c0 + r) * T_ + t0 + tl];
        }
#pragma unroll
        for (int ii = 0; ii < 4; ++ii) {
            int idx = tid * 4 + ii;
            ((float*)w1s)[idx] = W1[(size_t)c0 * H_ + idx];
        }
        __syncthreads();
#pragma unroll
        for (int i = 0; i < 64; ++i) {
            float s = xs[i][tl];
            float4 w = *(const float4*)&w1s[i][jg * 4];
            acc[0] = fmaf(s, w.x, acc[0]);
            acc[1] = fmaf(s, w.y, acc[1]);
            acc[2] = fmaf(s, w.z, acc[2]);
            acc[3] = fmaf(s, w.w, acc[3]);
        }
        __syncthreads();
    }
    float4 o; o.x = acc[0]; o.y = acc[1]; o.z = acc[2]; o.w = acc[3];
    *(float4*)&hx[(size_t)(t0 + tl) * H_ + jg * 4] = o;
}

// load 10 consecutive floats (8B-aligned) as 5x float2
#define LOAD10(dst, ptr)                                                      \
  { const float2* _p2 = (const float2*)(ptr);                                 \
    float2 _a0 = _p2[0], _a1 = _p2[1], _a2 = _p2[2], _a3 = _p2[3],            \
           _a4 = _p2[4];                                                      \
    dst[0] = _a0.x; dst[1] = _a0.y; dst[2] = _a1.x; dst[3] = _a1.y;           \
    dst[4] = _a2.x; dst[5] = _a2.y; dst[6] = _a3.x; dst[7] = _a3.y;           \
    dst[8] = _a4.x; dst[9] = _a4.y; }

// ---------------------------------------------------------------------------
// Scan: block 0 = 256 threads (4 waves, priority 3), thread = chans {2t,2t+1}.
// Blocks 1..256 = clock heaters (priority 0), ~1 per CU. Only tid==0 of each
// heater polls the global flag (~1 poll per 1024 cyc per block); everyone
// else spins on a block-local LDS flag — no fabric hot-line (R6 lesson).
// ---------------------------------------------------------------------------
#define STEP(TT, PH)                                                          \
  {                                                                           \
    const int tt = (TT);                                                      \
    /* ---- A ---- */                                                         \
    float4 R0 = rp4[0], R1 = rp4[1], R2 = rp4[2], R3 = rp4[3];                \
    float qa0 = b2c0, qb0 = 0.f, qa1 = b2c1, qb1 = 0.f;                       \
    qa0 = fmaf(R0.x, w2c0[0],  qa0); qa1 = fmaf(R0.x, w2c1[0],  qa1);         \
    qb0 = fmaf(R0.y, w2c0[1],  qb0); qb1 = fmaf(R0.y, w2c1[1],  qb1);         \
    qa0 = fmaf(R0.z, w2c0[2],  qa0); qa1 = fmaf(R0.z, w2c1[2],  qa1);         \
    qb0 = fmaf(R0.w, w2c0[3],  qb0); qb1 = fmaf(R0.w, w2c1[3],  qb1);         \
    qa0 = fmaf(R1.x, w2c0[4],  qa0); qa1 = fmaf(R1.x, w2c1[4],  qa1);         \
    qb0 = fmaf(R1.y, w2c0[5],  qb0); qb1 = fmaf(R1.y, w2c1[5],  qb1);         \
    qa0 = fmaf(R1.z, w2c0[6],  qa0); qa1 = fmaf(R1.z, w2c1[6],  qa1);         \
    qb0 = fmaf(R1.w, w2c0[7],  qb0); qb1 = fmaf(R1.w, w2c1[7],  qb1);         \
    qa0 = fmaf(R2.x, w2c0[8],  qa0); qa1 = fmaf(R2.x, w2c1[8],  qa1);         \
    qb0 = fmaf(R2.y, w2c0[9],  qb0); qb1 = fmaf(R2.y, w2c1[9],  qb1);         \
    qa0 = fmaf(R2.z, w2c0[10], qa0); qa1 = fmaf(R2.z, w2c1[10], qa1);         \
    qb0 = fmaf(R2.w, w2c0[11], qb0); qb1 = fmaf(R2.w, w2c1[11], qb1);         \
    qa0 = fmaf(R3.x, w2c0[12], qa0); qa1 = fmaf(R3.x, w2c1[12], qa1);         \
    qb0 = fmaf(R3.y, w2c0[13], qb0); qb1 = fmaf(R3.y, w2c1[13], qb1);         \
    qa0 = fmaf(R3.z, w2c0[14], qa0); qa1 = fmaf(R3.z, w2c1[14], qa1);         \
    qb0 = fmaf(R3.w, w2c0[15], qb0); qb1 = fmaf(R3.w, w2c1[15], qb1);         \
    const float q0 = qa0 + qb0, q1 = qa1 + qb1;                               \
    powv *= 0.95f;                                                            \
    const float mq0 = 0.05f * q0, mq1 = 0.05f * q1;                           \
    _Pragma("unroll")                                                         \
    for (int m = 0; m < M_; ++m) {                                            \
        ema0[m] = fmaf(ema0[m], 0.95f, mq0 * kq[PH][m]);                      \
        ema1[m] = fmaf(ema1[m], 0.95f, mq1 * kq[PH][5 + m]);                  \
    }                                                                         \
    float d0 = 0.f, d1 = 0.f, s0 = 0.f, s1 = 0.f;                             \
    _Pragma("unroll")                                                         \
    for (int m = 0; m < M_; ++m) {                                            \
        d0 = fmaf(ema0[m], vq[PH][m],     d0);                                \
        d1 = fmaf(ema1[m], vq[PH][5 + m], d1);                                \
        s0 = fmaf(ema0[m], ema0[m], s0);                                      \
        s1 = fmaf(ema1[m], ema1[m], s1);                                      \
    }                                                                         \
    float2 dw; dw.x = d0; dw.y = d1;                                          \
    ((float2*)sds)[tid] = dw;                                                 \
    /* K/V prefetch for row tt+4 — AFTER kq[PH]/vq[PH] were consumed */       \
    if (tt + 4 < T_) {                                                        \
        LOAD10(kq[PH], kp); LOAD10(vq[PH], vp);                               \
        kp += CM_; vp += CM_;                                                 \
    }                                                                         \
    float ssv = s0 + s1;                                                      \
    ssv = DPP_ADD(ssv, 0x111);  /* row_shr:1  */                              \
    ssv = DPP_ADD(ssv, 0x112);  /* row_shr:2  */                              \
    ssv = DPP_ADD(ssv, 0x114);  /* row_shr:4  */                              \
    ssv = DPP_ADD(ssv, 0x118);  /* row_shr:8  */                              \
    ssv = DPP_ADD(ssv, 0x142);  /* row_bcast15 */                             \
    ssv = DPP_ADD(ssv, 0x143);  /* row_bcast31 */                             \
    if ((tid & 63) == 63) rp[16 + (tid >> 6)] = ssv;                          \
    bar_lgkm();                                                               \
    /* ---- E ---- */                                                         \
    float4 ebuf[8];                                                           \
    _Pragma("unroll")                                                         \
    for (int i = 0; i < 8; ++i) ebuf[i] = sd4[16 * i + k16];                  \
    float4 P = *(const float4*)&rp[16];                                       \
    float nrm   = (P.x + P.y) + (P.z + P.w);                                  \
    float bias  = 1.0f - powv;                                                \
    float nr    = __builtin_amdgcn_sqrtf(nrm);                                \
    float scale = __builtin_amdgcn_rcpf(fmaf(1e-12f, bias, nr));              \
    o0[tt] = scale * d0;                                                      \
    o1[tt] = scale * d1;                                                      \
    float a0 = 0.f, a1 = 0.f, a2 = 0.f, a3 = 0.f;                             \
    _Pragma("unroll")                                                         \
    for (int i = 0; i < 8; ++i) {                                             \
        a0 = fmaf(ebuf[i].x, w1r[4 * i + 0], a0);                             \
        a1 = fmaf(ebuf[i].y, w1r[4 * i + 1], a1);                             \
        a2 = fmaf(ebuf[i].z, w1r[4 * i + 2], a2);                             \
        a3 = fmaf(ebuf[i].w, w1r[4 * i + 3], a3);                             \
    }                                                                         \
    float pu = (a0 + a1) + (a2 + a3);                                         \
    pu = DPP_ADD(pu, 0x111);                                                  \
    pu = DPP_ADD(pu, 0x112);                                                  \
    pu = DPP_ADD(pu, 0x114);                                                  \
    pu = DPP_ADD(pu, 0x118);  /* lane15 of each row: full u_j */              \
    if (k16 == 15) rp[j16] = fmaxf(fmaf(scale, pu, hxe[tt & 1]), 0.f);        \
    {                                                                         \
        int tn = tt + 3; if (tn > T_ - 1) tn = T_ - 1;                        \
        hxe[tt & 1] = hx[(size_t)tn * H_ + j16];                              \
    }                                                                         \
    bar_lgkm();                                                               \
  }

__global__ __launch_bounds__(256, 1) void scan_kernel(
    const float* __restrict__ hx, const float* __restrict__ Kp,
    const float* __restrict__ Vp, const float* __restrict__ W1,
    const float* __restrict__ W2, const float* __restrict__ b2,
    float* __restrict__ out)
{
    const int tid = threadIdx.x;

    if (blockIdx.x != 0) {
        // ---- heater: keep all CUs busy so DPM boosts SCLK. tid0 is the
        // only global poller (~1 poll / 1024 cyc / block); everyone else
        // spins on the LDS flag. No shared hot cacheline (R6 post-mortem).
        __shared__ unsigned hflag;
        if (tid == 0) hflag = 0;
        __syncthreads();
        __builtin_amdgcn_s_setprio(0);
        unsigned start = 0;
        if (tid == 0)
            start = __hip_atomic_load(&g_flag, __ATOMIC_RELAXED,
                                      __HIP_MEMORY_SCOPE_AGENT);
        float a0 = (float)(tid + blockIdx.x) * 1e-6f + 1.0f;
        float a1 = a0 + 0.25f, a2 = a0 + 0.5f, a3 = a0 + 0.75f;
        const float b = 1.0000001f, cc = 1e-7f;
        for (int it = 0; it < 100000; ++it) {
#pragma unroll
            for (int k = 0; k < 128; ++k) {
                a0 = fmaf(a0, b, cc); a1 = fmaf(a1, b, cc);
                a2 = fmaf(a2, b, cc); a3 = fmaf(a3, b, cc);
            }
            if (tid == 0 &&
                __hip_atomic_load(&g_flag, __ATOMIC_RELAXED,
                                  __HIP_MEMORY_SCOPE_AGENT) != start)
                __hip_atomic_store(&hflag, 1u, __ATOMIC_RELAXED,
                                   __HIP_MEMORY_SCOPE_WORKGROUP);
            if (__hip_atomic_load(&hflag, __ATOMIC_RELAXED,
                                  __HIP_MEMORY_SCOPE_WORKGROUP)) break;
        }
        if (__float_as_uint(a0 + a1 + a2 + a3) == 0xDEADBEEFu)  // keep live
            __hip_atomic_fetch_add(&g_flag, 0u, __ATOMIC_RELAXED,
                                   __HIP_MEMORY_SCOPE_AGENT);
        return;
    }

    __builtin_amdgcn_s_setprio(3);   // scan waves win issue arbitration

    const int c0  = 2 * tid, c1 = 2 * tid + 1;
    const int j16 = tid >> 4;
    const int k16 = tid & 15;

    __shared__ __align__(16) float sds[C_];   // d[0..511]
    __shared__ __align__(16) float rp[20];    // rh[0..15], ss partials [16..19]
    const float4* sd4 = (const float4*)sds;
    const float4* rp4 = (const float4*)rp;

    float w1r[32], w2c0[16], w2c1[16];
#pragma unroll
    for (int i = 0; i < 8; ++i)
#pragma unroll
        for (int l = 0; l < 4; ++l)
            w1r[4 * i + l] = W1[(size_t)(64 * i + 4 * k16 + l) * H_ + j16];
#pragma unroll
    for (int j = 0; j < 16; ++j) {
        w2c0[j] = W2[(size_t)j * C_ + c0];
        w2c1[j] = W2[(size_t)j * C_ + c1];
    }
    const float b2c0 = b2[c0], b2c1 = b2[c1];

    float ema0[M_] = {0, 0, 0, 0, 0};
    float ema1[M_] = {0, 0, 0, 0, 0};
    float powv = 1.0f;

    // K/V register prefetch, 4 steps deep
    const float* kp = Kp + 10 * tid;
    const float* vp = Vp + 10 * tid;
    float kq[4][10], vq[4][10];
#pragma unroll
    for (int ph = 0; ph < 4; ++ph) {
        LOAD10(kq[ph], kp + ph * CM_);
        LOAD10(vq[ph], vp + ph * CM_);
    }
    kp += 4 * CM_; vp += 4 * CM_;

    // hx scalar prefetch: slot t&1 holds hx[t+1][j16]
    float hxe[2];
    hxe[0] = hx[1 * H_ + j16];
    hxe[1] = hx[2 * H_ + j16];

    // seed rh for step 0: y_prev = 0 -> rh = relu(hx[0])
    if (tid < 16) rp[tid] = fmaxf(hx[tid], 0.f);
    __syncthreads();

    float* o0 = out + (size_t)c0 * T_;
    float* o1 = out + (size_t)c1 * T_;

    for (int t = 0; t < T_; t += 4) {
        STEP(t,     0)
        STEP(t + 1, 1)
        STEP(t + 2, 2)
        STEP(t + 3, 3)
    }

    if (tid == 0)
        __hip_atomic_fetch_add(&g_flag, 1u, __ATOMIC_RELAXED,
                               __HIP_MEMORY_SCOPE_AGENT);
}

extern "C" void kernel_launch(void* const* d_in, const int* in_sizes, int n_in,
                              void* d_out, int out_size, void* d_ws, size_t ws_size,
                              hipStream_t stream)
{
    (void)in_sizes; (void)n_in; (void)out_size; (void)ws_size;
    const float* y  = (const float*)d_in[0];
    const float* K  = (const float*)d_in[1];
    const float* V  = (const float*)d_in[2];
    const float* W1 = (const float*)d_in[3];
    const float* b1 = (const float*)d_in[4];
    const float* W2 = (const float*)d_in[5];
    const float* b2 = (const float*)d_in[6];
    float* out = (float*)d_out;
    float* hx  = (float*)d_ws;                 // T*16 floats = 512 KB

    hipLaunchKernelGGL(hx_kernel, dim3(T_ / 64), dim3(256), 0, stream,
                       y, W1, b1, hx);
    // 1 scan block + 256 heaters ≈ 1 heater per CU; all co-resident.
    hipLaunchKernelGGL(scan_kernel, dim3(257), dim3(256), 0, stream,
                       hx, K, V, W1, W2, b2, out);
}